// Round 1
// baseline (712.909 us; speedup 1.0000x reference)
//
#include <hip/hip_runtime.h>

#define N_NODES  50000
#define N_EDGES  800000
#define D_IN     64
#define D_RADIAL 128
#define NTILES   (N_EDGES / 64)   // 12500, exact

typedef __bf16 bf16x8 __attribute__((ext_vector_type(8)));
typedef float  f32x4  __attribute__((ext_vector_type(4)));
typedef short  s16x8  __attribute__((ext_vector_type(8)));

// pack two f32 -> two bf16 (truncation) in one v_perm
__device__ inline unsigned int pack_bf16_pair(float lo, float hi) {
    return __builtin_amdgcn_perm(__float_as_uint(hi), __float_as_uint(lo), 0x07060302u);
}

// round-to-nearest-even f32 -> bf16 (cold path: W only)
__device__ inline short f2bf_rne(float f) {
    unsigned int u = __float_as_uint(f);
    u += 0x7FFFu + ((u >> 16) & 1u);
    return (short)(u >> 16);
}

__global__ __launch_bounds__(256) void edge_msg_kernel(
    const float* __restrict__ x,        // [N, 64]
    const float* __restrict__ eb,       // [E, 128]
    const int*   __restrict__ src,      // [E]
    const int*   __restrict__ dst,      // [E]
    const float* __restrict__ W,        // [64, 128]
    const float* __restrict__ bias_p,   // [64]
    float*       __restrict__ out)      // [N, 64]
{
    const int lane = threadIdx.x & 63;
    const int wv   = threadIdx.x >> 6;   // wave 0..3 in block
    const int l15  = lane & 15;
    const int quad = lane >> 4;

    // ---- B-operand fragments of W' (W'[r][d] = W[d][r]); loaded once per block ----
    // frag(kt,nt) element j = W'[kt*32 + quad*8 + j][nt*16 + l15]
    bf16x8 wfrag[4][4];
    #pragma unroll
    for (int nt = 0; nt < 4; ++nt) {
        const int d = nt * 16 + l15;
        #pragma unroll
        for (int kt = 0; kt < 4; ++kt) {
            const float* p = W + d * D_RADIAL + kt * 32 + quad * 8;
            s16x8 s;
            #pragma unroll
            for (int j = 0; j < 8; ++j) s[j] = f2bf_rne(p[j]);
            wfrag[nt][kt] = __builtin_bit_cast(bf16x8, s);
        }
    }
    float bv[4];
    #pragma unroll
    for (int nt = 0; nt < 4; ++nt) bv[nt] = bias_p[nt * 16 + l15];

    for (int tile = blockIdx.x; tile < NTILES; tile += gridDim.x) {
        const int ebase = tile * 64 + wv * 16;   // this wave's 16 edges

        f32x4 acc[4];
        #pragma unroll
        for (int nt = 0; nt < 4; ++nt) acc[nt] = (f32x4){0.f, 0.f, 0.f, 0.f};

        // ---- K loop: 4 steps of 32 ----
        #pragma unroll
        for (int kt = 0; kt < 4; ++kt) {
            // A frag: EB[ebase + l15][kt*32 + quad*8 + j], 8 consecutive f32
            const float* p = eb + (long)(ebase + l15) * D_RADIAL + kt * 32 + quad * 8;
            f32x4 a0 = *(const f32x4*)(p);
            f32x4 a1 = *(const f32x4*)(p + 4);
            int4 packed;
            packed.x = pack_bf16_pair(a0[0], a0[1]);
            packed.y = pack_bf16_pair(a0[2], a0[3]);
            packed.z = pack_bf16_pair(a1[0], a1[1]);
            packed.w = pack_bf16_pair(a1[2], a1[3]);
            bf16x8 afrag = __builtin_bit_cast(bf16x8, packed);
            #pragma unroll
            for (int nt = 0; nt < 4; ++nt)
                acc[nt] = __builtin_amdgcn_mfma_f32_16x16x32_bf16(
                    afrag, wfrag[nt][kt], acc[nt], 0, 0, 0);
        }

        // ---- epilogue: D[row=quad*4+reg][col=l15]; e = ebase+row, d = nt*16+l15 ----
        const int erow = ebase + quad * 4;
        #pragma unroll
        for (int reg = 0; reg < 4; ++reg) {
            const int e  = erow + reg;
            const int sv = src[e];
            const int dv = dst[e];
            const float* xrow = x   + (long)sv * D_IN;
            float*       orow = out + (long)dv * D_IN;
            #pragma unroll
            for (int nt = 0; nt < 4; ++nt) {
                const int d = nt * 16 + l15;
                const float val = (acc[nt][reg] + bv[nt]) * xrow[d];
                unsafeAtomicAdd(orow + d, val);
            }
        }
    }
}

extern "C" void kernel_launch(void* const* d_in, const int* in_sizes, int n_in,
                              void* d_out, int out_size, void* d_ws, size_t ws_size,
                              hipStream_t stream) {
    const float* x    = (const float*)d_in[0];
    const float* eb   = (const float*)d_in[1];
    const int*   src  = (const int*)d_in[2];
    const int*   dst  = (const int*)d_in[3];
    const float* W    = (const float*)d_in[4];
    const float* bias = (const float*)d_in[5];
    float* out = (float*)d_out;

    // harness poisons d_out with 0xAA before every launch — zero it first
    hipMemsetAsync(d_out, 0, (size_t)N_NODES * D_IN * sizeof(float), stream);

    edge_msg_kernel<<<1024, 256, 0, stream>>>(x, eb, src, dst, W, bias, out);
}